// Round 4
// baseline (1274.398 us; speedup 1.0000x reference)
//
#include <hip/hip_runtime.h>

// out[e] = segment_sum(M, dest)[src[e]] - M[rev_index[e]]
// E = 800,000, D = 64 (fp32), N_NODES = 50,000.
//
// Round-4 structure: coarse radix-partition aggregation (all-streaming), then
// the unavoidable random gather for M[rev[e]].
//   K1 hist   : LDS-privatized histogram of dest>>7 (NB=391 coarse buckets)
//   K2 scan   : exclusive scan of 391 counts (+cursor copy)
//   K3 scatter: stream M, append each 256 B row to its coarse bucket
//               (~391 concurrent sequential write streams ~ DRAM page friendly,
//                NOT 50k-way random like round 2)
//   K4 reduce : block per bucket; contiguous streaming read; per-node f32
//               accumulators in LDS (ds_add_f32); coalesced Mv write
//   K5 gather : out[e] = Mv[src[e]] - M[rev[e]]; nt stores
// Measured facts driving this: random-granule HBM = ~1.4 TB/s either direction
// (r2/r3); fp32 global atomics write through LLC at 16 B/op (r3, 683 us);
// gather alone is ~300 us (r3 subtraction) and is the next target.

#define D 64
#define N_NODES 50000
#define W 128                        // nodes per coarse bucket (dest >> 7)
#define NB ((N_NODES + W - 1) / W)   // 391
#define ACC_STRIDE 68                // 64 + 4 pad: breaks LDS bank aliasing
#define SCAN_THREADS 1024

typedef float f4 __attribute__((ext_vector_type(4)));

// K1: coarse histogram, LDS-privatized (global atomics: 391 per block only).
__global__ void agg_hist(const int* __restrict__ dest, int* __restrict__ counts, int E) {
    __shared__ int h[NB];
    for (int i = threadIdx.x; i < NB; i += blockDim.x) h[i] = 0;
    __syncthreads();
    int t = blockIdx.x * blockDim.x + threadIdx.x;
    int e = t << 2;
    if (e + 3 < E) {
        int4 d = *reinterpret_cast<const int4*>(dest + e);
        atomicAdd(&h[d.x >> 7], 1);
        atomicAdd(&h[d.y >> 7], 1);
        atomicAdd(&h[d.z >> 7], 1);
        atomicAdd(&h[d.w >> 7], 1);
    } else {
        for (; e < E; ++e) atomicAdd(&h[dest[e] >> 7], 1);
    }
    __syncthreads();
    for (int i = threadIdx.x; i < NB; i += blockDim.x)
        if (h[i]) atomicAdd(counts + i, h[i]);
}

// K2: single-block exclusive scan of N entries; writes cursor copy; data[N]=total.
__global__ void agg_scan(int* __restrict__ data, int* __restrict__ cursor, int N) {
    __shared__ int wsums[SCAN_THREADS / 64];
    __shared__ int carry_sh;
    const int t = threadIdx.x;
    const int lane = t & 63;
    const int w = t >> 6;
    if (t == 0) carry_sh = 0;
    __syncthreads();
    for (int base = 0; base < N; base += SCAN_THREADS) {
        int i = base + t;
        int v = (i < N) ? data[i] : 0;
        int carry = carry_sh;
        int x = v;
        #pragma unroll
        for (int off = 1; off < 64; off <<= 1) {
            int y = __shfl_up(x, off, 64);
            if (lane >= off) x += y;
        }
        if (lane == 63) wsums[w] = x;
        __syncthreads();
        if (t == 0) {
            int run = 0;
            #pragma unroll
            for (int k = 0; k < SCAN_THREADS / 64; ++k) {
                int c = wsums[k]; wsums[k] = run; run += c;
            }
            carry_sh = carry + run;
        }
        __syncthreads();
        int excl = carry + wsums[w] + (x - v);
        if (i < N) { data[i] = excl; cursor[i] = excl; }
        __syncthreads();
    }
    if (t == 0) { data[N] = carry_sh; cursor[N] = carry_sh; }
}

// K3: stream M, scatter rows to coarse buckets. 16 lanes/edge, float4 each.
// Writes within a bucket are cursor-ascending -> ~391 sequential write streams.
__global__ void agg_scatter(const float* __restrict__ M,
                            const int* __restrict__ dest,
                            int* __restrict__ cursor,
                            float* __restrict__ Msort,
                            int* __restrict__ destsort, int E) {
    int gid = blockIdx.x * blockDim.x + threadIdx.x;
    int e  = gid >> 4;
    int c4 = gid & 15;
    if (e >= E) return;
    f4 v = reinterpret_cast<const f4*>(M + (size_t)e * D)[c4];  // streaming read
    int d = dest[e];
    int pos = 0;
    if (c4 == 0) {
        pos = atomicAdd(cursor + (d >> 7), 1);
        destsort[pos] = d;
    }
    pos = __shfl(pos, (threadIdx.x & 63) & ~15, 64);  // broadcast in 16-group
    reinterpret_cast<f4*>(Msort + (size_t)pos * D)[c4] = v;
}

// K4: one block per bucket. Streaming read of contiguous bucket rows;
// accumulate into LDS per-node accumulators via native LDS f32 atomics.
__global__ __launch_bounds__(256) void agg_bucket_reduce(
        const float* __restrict__ Msort,
        const int* __restrict__ destsort,
        const int* __restrict__ offsets,
        float* __restrict__ Mv) {
    __shared__ float acc[W * ACC_STRIDE];   // 128*68*4 = 34.8 KB
    int b = blockIdx.x;
    int t = threadIdx.x;
    for (int i = t; i < W * ACC_STRIDE; i += 256) acc[i] = 0.f;
    __syncthreads();
    int beg = offsets[b], end = offsets[b + 1];
    int c4 = t & 15;
    for (int i = beg + (t >> 4); i < end; i += 16) {   // 16 rows / iter / block
        f4 v = reinterpret_cast<const f4*>(Msort)[(size_t)i * 16 + c4];
        int idx = destsort[i] & (W - 1);
        float* a = acc + idx * ACC_STRIDE + c4 * 4;
        atomicAdd(a + 0, v.x);
        atomicAdd(a + 1, v.y);
        atomicAdd(a + 2, v.z);
        atomicAdd(a + 3, v.w);
    }
    __syncthreads();
    int base = b * W;
    for (int j = t; j < W * 16; j += 256) {            // coalesced Mv write
        int r = j >> 4, q = j & 15;
        int node = base + r;
        if (node < N_NODES) {
            const float* a = acc + r * ACC_STRIDE + q * 4;
            f4 o = {a[0], a[1], a[2], a[3]};
            reinterpret_cast<f4*>(Mv)[(size_t)node * 16 + q] = o;
        }
    }
}

// K5: out[e] = Mv[src[e]] - M[rev[e]], 16 threads/edge, float4 each, nt stores.
__global__ void agg_gather(const float* __restrict__ Mv,
                           const float* __restrict__ M,
                           const int* __restrict__ src,
                           const int* __restrict__ rev,
                           float* __restrict__ out,
                           int E) {
    int gid = blockIdx.x * blockDim.x + threadIdx.x;
    int e  = gid >> 4;
    int c4 = gid & 15;
    if (e >= E) return;
    int s = src[e];
    int r = rev[e];
    f4 a = reinterpret_cast<const f4*>(Mv + (size_t)s * D)[c4];
    f4 b = reinterpret_cast<const f4*>(M  + (size_t)r * D)[c4];
    f4 o = a - b;
    __builtin_nontemporal_store(o, reinterpret_cast<f4*>(out + (size_t)e * D) + c4);
}

extern "C" void kernel_launch(void* const* d_in, const int* in_sizes, int n_in,
                              void* d_out, int out_size, void* d_ws, size_t ws_size,
                              hipStream_t stream) {
    const float* M   = (const float*)d_in[0];
    const int*   ei  = (const int*)d_in[1];   // (2, E) row-major: [src | dest]
    const int*   rev = (const int*)d_in[2];

    int E = in_sizes[0] / D;                  // 800,000
    const int* src  = ei;
    const int* dest = ei + E;

    // Workspace: small, proven-size region first.
    int*   offsets  = (int*)d_ws;                        // NB+1 (pad to 512)
    int*   cursor   = offsets + 512;                     // NB+1 (pad to 512)
    int*   destsort = cursor + 512;                      // E ints = 3.2 MB
    float* Mv       = (float*)(destsort + ((E + 63) & ~63));  // 12.8 MB
    float* ws_tail  = Mv + (size_t)N_NODES * D;
    size_t used     = (size_t)((char*)ws_tail - (char*)d_ws);

    // Msort (204.8 MB): put in ws if it provably fits, else borrow d_out
    // (safe: fully consumed by K4 before K5 overwrites out).
    size_t msort_bytes = (size_t)E * D * sizeof(float);
    float* Msort = (ws_size >= used + msort_bytes + 256)
                 ? (float*)(((uintptr_t)ws_tail + 255) & ~(uintptr_t)255)
                 : (float*)d_out;

    hipMemsetAsync(offsets, 0, (NB + 1) * sizeof(int), stream);

    int hb = ((E + 3) / 4 + 255) / 256;
    agg_hist<<<hb, 256, 0, stream>>>(dest, offsets, E);
    agg_scan<<<1, SCAN_THREADS, 0, stream>>>(offsets, cursor, NB);

    int sb = (int)(((size_t)E * 16 + 255) / 256);
    agg_scatter<<<sb, 256, 0, stream>>>(M, dest, cursor, Msort, destsort, E);
    agg_bucket_reduce<<<NB, 256, 0, stream>>>(Msort, destsort, offsets, Mv);

    agg_gather<<<sb, 256, 0, stream>>>(Mv, M, src, rev, (float*)d_out, E);
}

// Round 5
// 496.685 us; speedup vs baseline: 2.5658x; 2.5658x over previous
//
#include <hip/hip_runtime.h>

// out[e] = segment_sum(M, dest)[src[e]] - M[rev_index[e]]
// E = 800,000, D = 64 (fp32), N_NODES = 50,000.
//
// Round-5: revert to the round-1 CSR pipeline (best: 540 us) with three fixes:
//  - scan replaced by wave-aggregated atomic allocation (order within a node is
//    irrelevant for a sum; r3 proved the harness tolerates nondeterministic
//    accumulation). Kills the single-block 49-tile scan.
//  - gather processes 2 edges per 16-lane group -> 4 outstanding 256B row
//    loads per thread (latency x MLP).
//  - reduce uses fully-predicated 8-deep batches (no serial scalar tail).
// Measured rules honored: no hot-line atomics (r4), no fp32 global atomics
// (r3), no random-granule restructuring (r2) -- reduce streams/covers M so the
// gather's M[rev] reads hit LLC; nt stores keep the out stream from evicting M.

#define D 64
#define N_NODES 50000

typedef float f4 __attribute__((ext_vector_type(4)));

// K1: histogram of dest, 4 edges/thread via int4. 800K atomics over 50K
// addresses (~6250 cache lines) -> well below the per-line serialization limit.
__global__ void agg_hist(const int* __restrict__ dest, int* __restrict__ counts, int E) {
    int t = blockIdx.x * blockDim.x + threadIdx.x;
    int e = t << 2;
    if (e + 3 < E) {
        int4 d = *reinterpret_cast<const int4*>(dest + e);
        atomicAdd(counts + d.x, 1);
        atomicAdd(counts + d.y, 1);
        atomicAdd(counts + d.z, 1);
        atomicAdd(counts + d.w, 1);
    } else {
        for (; e < E; ++e) atomicAdd(counts + dest[e], 1);
    }
}

// K2: wave-aggregated segment-start allocation. Replaces the exclusive scan:
// per wave, shfl-scan 64 counts, ONE spread atomic for the wave total.
__global__ void agg_alloc(const int* __restrict__ counts,
                          int* __restrict__ starts,
                          int* __restrict__ cursor,
                          int* __restrict__ gtotal, int N) {
    int n = blockIdx.x * blockDim.x + threadIdx.x;
    int lane = threadIdx.x & 63;
    int c = (n < N) ? counts[n] : 0;
    int x = c;
    #pragma unroll
    for (int off = 1; off < 64; off <<= 1) {
        int y = __shfl_up(x, off, 64);
        if (lane >= off) x += y;
    }
    int base = 0;
    if (lane == 63) base = atomicAdd(gtotal, x);
    base = __shfl(base, 63, 64);
    int s = base + x - c;
    if (n < N) { starts[n] = s; cursor[n] = s; }
}

// K3: bin edge ids by dest, 4 edges/thread.
__global__ void agg_bin(const int* __restrict__ dest, int* __restrict__ cursor,
                        int* __restrict__ order, int E) {
    int t = blockIdx.x * blockDim.x + threadIdx.x;
    int e = t << 2;
    if (e + 3 < E) {
        int4 d = *reinterpret_cast<const int4*>(dest + e);
        int p0 = atomicAdd(cursor + d.x, 1); order[p0] = e;
        int p1 = atomicAdd(cursor + d.y, 1); order[p1] = e + 1;
        int p2 = atomicAdd(cursor + d.z, 1); order[p2] = e + 2;
        int p3 = atomicAdd(cursor + d.w, 1); order[p3] = e + 3;
    } else {
        for (; e < E; ++e) {
            int pos = atomicAdd(cursor + dest[e], 1);
            order[pos] = e;
        }
    }
}

// K4: one wave per node; lane = feature dim. Fully-predicated 8-deep batches:
// clamped indices + masked adds keep 8 loads in flight even in the tail.
// Side effect: covers ALL of M -> primes LLC for the gather.
__global__ void agg_reduce(const float* __restrict__ M,
                           const int* __restrict__ order,
                           const int* __restrict__ starts,
                           const int* __restrict__ counts,
                           float* __restrict__ Mv) {
    int lane = threadIdx.x & 63;
    int node = (blockIdx.x * blockDim.x + threadIdx.x) >> 6;
    if (node >= N_NODES) return;
    int beg = starts[node];
    int end = beg + counts[node];
    float acc0 = 0.f, acc1 = 0.f, acc2 = 0.f, acc3 = 0.f;
    for (int i = beg; i < end; i += 8) {
        int j1 = (i + 1 < end) ? i + 1 : beg;
        int j2 = (i + 2 < end) ? i + 2 : beg;
        int j3 = (i + 3 < end) ? i + 3 : beg;
        int j4 = (i + 4 < end) ? i + 4 : beg;
        int j5 = (i + 5 < end) ? i + 5 : beg;
        int j6 = (i + 6 < end) ? i + 6 : beg;
        int j7 = (i + 7 < end) ? i + 7 : beg;
        int e0 = order[i];
        int e1 = order[j1], e2 = order[j2], e3 = order[j3];
        int e4 = order[j4], e5 = order[j5], e6 = order[j6], e7 = order[j7];
        float a0 = M[(size_t)e0 * D + lane];
        float a1 = M[(size_t)e1 * D + lane];
        float a2 = M[(size_t)e2 * D + lane];
        float a3 = M[(size_t)e3 * D + lane];
        float a4 = M[(size_t)e4 * D + lane];
        float a5 = M[(size_t)e5 * D + lane];
        float a6 = M[(size_t)e6 * D + lane];
        float a7 = M[(size_t)e7 * D + lane];
        a1 = (i + 1 < end) ? a1 : 0.f;
        a2 = (i + 2 < end) ? a2 : 0.f;
        a3 = (i + 3 < end) ? a3 : 0.f;
        a4 = (i + 4 < end) ? a4 : 0.f;
        a5 = (i + 5 < end) ? a5 : 0.f;
        a6 = (i + 6 < end) ? a6 : 0.f;
        a7 = (i + 7 < end) ? a7 : 0.f;
        acc0 += a0 + a4;
        acc1 += a1 + a5;
        acc2 += a2 + a6;
        acc3 += a3 + a7;
    }
    Mv[(size_t)node * D + lane] = (acc0 + acc1) + (acc2 + acc3);
}

// K5: out[e] = Mv[src[e]] - M[rev[e]]. 2 edges per 16-lane group -> 4
// outstanding 256B-row loads per thread. nt stores: out is never re-read.
__global__ void agg_gather(const float* __restrict__ Mv,
                           const float* __restrict__ M,
                           const int* __restrict__ src,
                           const int* __restrict__ rev,
                           float* __restrict__ out,
                           int E) {
    int gid = blockIdx.x * blockDim.x + threadIdx.x;
    int p  = gid >> 4;
    int c4 = gid & 15;
    int e0 = p << 1;
    if (e0 >= E) return;
    int e1 = e0 + 1;
    int e1c = (e1 < E) ? e1 : e0;
    int s0 = src[e0], r0 = rev[e0];
    int s1 = src[e1c], r1 = rev[e1c];
    f4 a0 = reinterpret_cast<const f4*>(Mv + (size_t)s0 * D)[c4];
    f4 b0 = reinterpret_cast<const f4*>(M  + (size_t)r0 * D)[c4];
    f4 a1 = reinterpret_cast<const f4*>(Mv + (size_t)s1 * D)[c4];
    f4 b1 = reinterpret_cast<const f4*>(M  + (size_t)r1 * D)[c4];
    f4 o0 = a0 - b0;
    __builtin_nontemporal_store(o0, reinterpret_cast<f4*>(out + (size_t)e0 * D) + c4);
    if (e1 < E) {
        f4 o1 = a1 - b1;
        __builtin_nontemporal_store(o1, reinterpret_cast<f4*>(out + (size_t)e1 * D) + c4);
    }
}

extern "C" void kernel_launch(void* const* d_in, const int* in_sizes, int n_in,
                              void* d_out, int out_size, void* d_ws, size_t ws_size,
                              hipStream_t stream) {
    const float* M   = (const float*)d_in[0];
    const int*   ei  = (const int*)d_in[1];   // (2, E) row-major: [src | dest]
    const int*   rev = (const int*)d_in[2];

    int E = in_sizes[0] / D;                  // 800,000
    const int* src  = ei;
    const int* dest = ei + E;

    // Workspace (~16.3 MB, well under the proven r1 budget)
    int*   counts = (int*)d_ws;                        // 50,176 ints
    int*   gtotal = counts + 50176;                    // 64 ints (1 used)
    int*   starts = gtotal + 64;                       // 50,176 ints
    int*   cursor = starts + 50176;                    // 50,176 ints
    int*   order  = cursor + 50176;                    // E ints
    float* Mv     = (float*)(order + ((E + 63) & ~63)); // 12.8 MB

    // zero counts + gtotal in one memset
    hipMemsetAsync(counts, 0, (50176 + 64) * sizeof(int), stream);

    int hb = ((E + 3) / 4 + 255) / 256;
    agg_hist<<<hb, 256, 0, stream>>>(dest, counts, E);

    int ab = (N_NODES + 255) / 256;
    agg_alloc<<<ab, 256, 0, stream>>>(counts, starts, cursor, gtotal, N_NODES);

    agg_bin<<<hb, 256, 0, stream>>>(dest, cursor, order, E);

    int rb = (N_NODES * 64 + 255) / 256;      // one wave per node
    agg_reduce<<<rb, 256, 0, stream>>>(M, order, starts, counts, Mv);

    int gb = (int)(((size_t)(E / 2) * 16 + 255) / 256);
    agg_gather<<<gb, 256, 0, stream>>>(Mv, M, src, rev, (float*)d_out, E);
}